// Round 8
// baseline (2868.005 us; speedup 1.0000x reference)
//
#include <hip/hip_runtime.h>

// Bidirectional LSTM: B=64, T=512, D=512 (feats k=h*64+c), U=256.
// W: [768,1024] fp32, gate order (i,j,f,o), forget bias 1.0.
// out [64,512,512] fp32 (fw units 0..255, bw 256..511), bw aligned to t.
//
// Structure = round-3 kernel (PASSED, rec_persist 2397us), minimally edited:
//  - out-store + xz prefetch issued BEFORE the first poll (their HBM latency
//    drains inside the first spin round, never inside a retry).
//  - two-phase poll: cheap 32B/thread SENTINEL spin (1 tagged dword per
//    slice for this thread's row, all 8 producers) -> 64KB bulk read that
//    still SELF-VALIDATES every word (re-bulk if stale; rare). Spin traffic
//    8x lower -> no L2 self-congestion against the producers' publishes.
//  - every multi-load asm block has EARLY-CLOBBER outputs (round-4 lesson).
// Protocol unchanged: tagged words (tag<<16)|f16, XCD-local L2 via sc0,
// XCC_ID claim pins 8 wgs/dir to one XCD, bounded spins (never hangs).

typedef float f32x4 __attribute__((ext_vector_type(4)));
typedef _Float16 f16;
typedef _Float16 f16x4 __attribute__((ext_vector_type(4)));
typedef _Float16 f16x8 __attribute__((ext_vector_type(8)));
typedef unsigned int u32;
typedef unsigned int u32x4 __attribute__((ext_vector_type(4)));
typedef unsigned long long u64;

// ---------------------------------------------------------------- init
__global__ void init_all(const float* __restrict__ Wfw, const float* __restrict__ Wbw,
                         f16* __restrict__ wrec2, u32* __restrict__ hbuf) {
    const int i = blockIdx.x * blockDim.x + threadIdx.x;   // 0..524287
    const int dir = i >> 18;
    const int rem = i & 0x3FFFF;
    const int col = rem >> 8;        // 0..1023 : sl*128 + gg*32 + uu
    const int k   = rem & 255;
    const int sl  = col >> 7;
    const int gg  = (col & 127) >> 5;
    const int uu  = col & 31;
    const float* W = dir ? Wbw : Wfw;
    wrec2[i] = (f16)W[(size_t)(512 + k) * 1024 + gg * 256 + sl * 32 + uu];
    // tagged-h double buffer (65536 u32) + 8 claim counters.
    // zero = {tag 0, h 0.0f16} = valid initial state for step 0.
    if (i < 65544) hbuf[i] = 0u;
}

// ---------------------------------------------------------------- xz GEMM
#define BM 128
#define BN 128
#define BK 32
#define ASTR 40   // f16 per LDS row (32 + 8 pad)

__global__ __launch_bounds__(256)
void gemm_xz(const float* __restrict__ x,
             const float* __restrict__ Wfw, const float* __restrict__ Wbw,
             const float* __restrict__ bfw, const float* __restrict__ bbw,
             f16* __restrict__ xz_fw, f16* __restrict__ xz_bw) {
    const int dir = blockIdx.z;
    const float* __restrict__ W    = dir ? Wbw : Wfw;
    const float* __restrict__ bias = dir ? bbw : bfw;
    f16* __restrict__ xz = dir ? xz_bw : xz_fw;

    __shared__ __align__(16) f16 As[BM * ASTR];
    __shared__ __align__(16) f16 Bs[BN * ASTR];

    const int tid = threadIdx.x;
    const int m0 = blockIdx.x * BM;
    const int n0 = blockIdx.y * BN;

    const int lane = tid & 63;
    const int wave = tid >> 6;
    const int wm = (wave & 1) * 64;
    const int wn = (wave >> 1) * 64;
    const int mi = lane & 15;
    const int kq = lane >> 4;

    const int arow = tid >> 1;
    const int ahalf = (tid & 1) * 16;
    const int am = m0 + arow;
    const int bb = am >> 9;            // batch (T=512)
    const int t  = am & 511;
    const int kk = tid >> 3;
    const int nc = (tid & 7) * 16;

    f32x4 acc[4][4];
#pragma unroll
    for (int i = 0; i < 4; i++)
#pragma unroll
        for (int j = 0; j < 4; j++) acc[i][j] = (f32x4)0.f;

    for (int kt = 0; kt < 512; kt += BK) {
        float va[16], vb[16];
        {
            const int kbase = kt + ahalf;
            const int hh = kbase >> 6;
            const float* px = x + (((size_t)bb * 8 + hh) * 512 + t) * 64 + (kbase & 63);
#pragma unroll
            for (int i = 0; i < 4; i++) {
                f32x4 v = *(const f32x4*)(px + i * 4);
                va[i*4+0] = v[0]; va[i*4+1] = v[1]; va[i*4+2] = v[2]; va[i*4+3] = v[3];
            }
            const float* pw = W + (size_t)(kt + kk) * 1024 + n0 + nc;
#pragma unroll
            for (int i = 0; i < 4; i++) {
                f32x4 v = *(const f32x4*)(pw + i * 4);
                vb[i*4+0] = v[0]; vb[i*4+1] = v[1]; vb[i*4+2] = v[2]; vb[i*4+3] = v[3];
            }
        }
        __syncthreads();
        {
            f16* pa = &As[arow * ASTR + ahalf];
#pragma unroll
            for (int i = 0; i < 4; i++) {
                f16x4 s;
                s[0] = (f16)va[i*4+0]; s[1] = (f16)va[i*4+1];
                s[2] = (f16)va[i*4+2]; s[3] = (f16)va[i*4+3];
                *(f16x4*)(pa + i * 4) = s;
            }
#pragma unroll
            for (int i = 0; i < 16; i++)
                Bs[(nc + i) * ASTR + kk] = (f16)vb[i];
        }
        __syncthreads();
        f16x8 afr[4], bfr[4];
#pragma unroll
        for (int mt = 0; mt < 4; mt++)
            afr[mt] = *(const f16x8*)(&As[(wm + mt * 16 + mi) * ASTR + kq * 8]);
#pragma unroll
        for (int nt = 0; nt < 4; nt++)
            bfr[nt] = *(const f16x8*)(&Bs[(wn + nt * 16 + mi) * ASTR + kq * 8]);
#pragma unroll
        for (int mt = 0; mt < 4; mt++)
#pragma unroll
            for (int nt = 0; nt < 4; nt++)
                acc[mt][nt] = __builtin_amdgcn_mfma_f32_16x16x32_f16(
                    afr[mt], bfr[nt], acc[mt][nt], 0, 0, 0);
    }

    const int col = lane & 15;
    const int rbase = kq * 4;
#pragma unroll
    for (int mt = 0; mt < 4; mt++) {
#pragma unroll
        for (int nt = 0; nt < 4; nt++) {
            const int n = n0 + wn + nt * 16 + col;
            const float bv = bias[n];
#pragma unroll
            for (int r = 0; r < 4; r++) {
                const int mrow = m0 + wm + mt * 16 + rbase + r;
                xz[(size_t)mrow * 1024 + n] = (f16)(acc[mt][nt][r] + bv);
            }
        }
    }
}

// ---------------------------------------------------------------- recurrence
#define AP 264    // A_lds row stride (f16): 256 + 8 pad
#define ZP 67     // z_lds row stride (f32)
#define MAXSPIN_SENT 20000
#define MAXBULK 64

// Sentinel: 8 x global_load_dword sc0 at 128B stride (one tagged word per
// slice for this thread's row) + vmcnt(0). 32B/thread per spin round.
#define SENT8(sv, ap)                                                         \
    asm volatile(                                                             \
        "global_load_dword %0, %8, off sc0\n\t"                               \
        "global_load_dword %1, %8, off offset:128 sc0\n\t"                    \
        "global_load_dword %2, %8, off offset:256 sc0\n\t"                    \
        "global_load_dword %3, %8, off offset:384 sc0\n\t"                    \
        "global_load_dword %4, %8, off offset:512 sc0\n\t"                    \
        "global_load_dword %5, %8, off offset:640 sc0\n\t"                    \
        "global_load_dword %6, %8, off offset:768 sc0\n\t"                    \
        "global_load_dword %7, %8, off offset:896 sc0\n\t"                    \
        "s_waitcnt vmcnt(0)"                                                  \
        : "=&v"(sv[0]), "=&v"(sv[1]), "=&v"(sv[2]), "=&v"(sv[3]),             \
          "=&v"(sv[4]), "=&v"(sv[5]), "=&v"(sv[6]), "=&v"(sv[7])              \
        : "v"(ap)                                                             \
        : "memory")

// Bulk: 16 x global_load_dwordx4 sc0 covering this thread's full row slice
// (1KB/thread total across the wg = the whole 64KB h buffer). EARLY-CLOBBER.
#define BULK16(qv, ap)                                                        \
    asm volatile(                                                             \
        "global_load_dwordx4 %0, %16, off sc0\n\t"                            \
        "global_load_dwordx4 %1, %16, off offset:64 sc0\n\t"                  \
        "global_load_dwordx4 %2, %16, off offset:128 sc0\n\t"                 \
        "global_load_dwordx4 %3, %16, off offset:192 sc0\n\t"                 \
        "global_load_dwordx4 %4, %16, off offset:256 sc0\n\t"                 \
        "global_load_dwordx4 %5, %16, off offset:320 sc0\n\t"                 \
        "global_load_dwordx4 %6, %16, off offset:384 sc0\n\t"                 \
        "global_load_dwordx4 %7, %16, off offset:448 sc0\n\t"                 \
        "global_load_dwordx4 %8, %16, off offset:512 sc0\n\t"                 \
        "global_load_dwordx4 %9, %16, off offset:576 sc0\n\t"                 \
        "global_load_dwordx4 %10, %16, off offset:640 sc0\n\t"                \
        "global_load_dwordx4 %11, %16, off offset:704 sc0\n\t"                \
        "global_load_dwordx4 %12, %16, off offset:768 sc0\n\t"                \
        "global_load_dwordx4 %13, %16, off offset:832 sc0\n\t"                \
        "global_load_dwordx4 %14, %16, off offset:896 sc0\n\t"                \
        "global_load_dwordx4 %15, %16, off offset:960 sc0\n\t"                \
        "s_waitcnt vmcnt(0)"                                                  \
        : "=&v"(qv[0]), "=&v"(qv[1]), "=&v"(qv[2]), "=&v"(qv[3]),             \
          "=&v"(qv[4]), "=&v"(qv[5]), "=&v"(qv[6]), "=&v"(qv[7]),             \
          "=&v"(qv[8]), "=&v"(qv[9]), "=&v"(qv[10]), "=&v"(qv[11]),           \
          "=&v"(qv[12]), "=&v"(qv[13]), "=&v"(qv[14]), "=&v"(qv[15])          \
        : "v"(ap)                                                             \
        : "memory")

__global__ __launch_bounds__(256, 1)
void rec_persist(const f16* __restrict__ xz, const f16* __restrict__ wrec2,
                 u32* __restrict__ hbuf, u32* __restrict__ claimctr,
                 float* __restrict__ out) {
    // ---- XCD-claim: first 8 wgs on XCD0 -> dir0, first 8 on XCD1 -> dir1
    __shared__ int cs[2];
    if (threadIdx.x == 0) {
        u32 xcd;
        asm("s_getreg_b32 %0, hwreg(HW_REG_XCC_ID, 0, 32)" : "=s"(xcd));
        int d = -1, slv = 0;
        if (xcd < 2u) {
            u32 slot = atomicAdd(&claimctr[xcd], 1u);
            if (slot < 8u) { d = (int)xcd; slv = (int)slot; }
        }
        cs[0] = d; cs[1] = slv;
    }
    __syncthreads();
    const int dir = cs[0];
    const int sl  = cs[1];
    if (dir < 0) return;

    const f16* __restrict__ xzd = xz + (size_t)dir * 64 * 512 * 1024;
    const f16* __restrict__ wsl = wrec2 + ((size_t)dir * 1024 + sl * 128) * 256;
    u32* __restrict__ hbd = hbuf + (size_t)dir * 2 * 64 * 256;

    __shared__ __align__(16) f16  A_lds[64 * AP];
    __shared__ float z_lds[128 * ZP];

    const int tid = threadIdx.x;
    const int lane = tid & 63;
    const int w = tid >> 6;
    const int r = w >> 1, c = w & 1;   // 2x2 wave tiling
    const int mi = lane & 15, kq = lane >> 4;

    // recurrent weight slab resident in registers: 32 frags = 128 VGPRs
    f16x8 Bf[4][8];
#pragma unroll
    for (int nt = 0; nt < 4; nt++)
#pragma unroll
        for (int ks = 0; ks < 8; ks++)
            Bf[nt][ks] = *(const f16x8*)(wsl + (size_t)(c * 64 + nt * 16 + mi) * 256
                                             + ks * 32 + kq * 8);

    const int b_act = tid >> 2;        // batch row (0..63)
    const int ug = tid & 3;            // unit-octet within slice
    float cell[8];
#pragma unroll
    for (int j = 0; j < 8; j++) cell[j] = 0.f;

    const int sm = tid >> 2;           // staging: batch row (same as b_act)

    float pv[8];                       // deferred out values
    int   pt = 0;

    float* const outb = out + ((size_t)b_act * 512) * 512 + dir * 256 + sl * 32 + ug * 8;

    for (int s = 0; s < 512; s++) {
        const int t = dir ? (511 - s) : s;
        const u32 tp = (u32)s << 16;

        // ---- HBM traffic first: out-store (prev step) + xz prefetch; their
        //      latency drains inside the first sentinel round ----
        if (s) {
            float* op = outb + (size_t)pt * 512;
            f32x4 o0 = {pv[0], pv[1], pv[2], pv[3]};
            f32x4 o1 = {pv[4], pv[5], pv[6], pv[7]};
            *(f32x4*)op = o0;
            *(f32x4*)(op + 4) = o1;
        }
        f16x8 xzv[4];
        const f16* xp = xzd + ((size_t)b_act * 512 + t) * 1024 + sl * 32 + ug * 8;
#pragma unroll
        for (int g = 0; g < 4; g++) xzv[g] = *(const f16x8*)(xp + g * 256);

        const char* rowb = (const char*)(hbd + (s & 1) * (64 * 256))
                         + (size_t)sm * 1024;

        // ---- phase 1: sentinel spin (32B/thread/round, all 8 slices) ----
        {
            const char* sp = rowb + ug * 32;
            u32 sv[8];
            int spins = 0;
            for (;;) {
                SENT8(sv, sp);
                u32 bad = 0;
#pragma unroll
                for (int i = 0; i < 8; i++) bad |= (sv[i] ^ tp);
                if (!__any((int)((bad & 0xFFFF0000u) != 0))) break;
                if (++spins > MAXSPIN_SENT) break;   // fail-safe, never hang
            }
        }

        // ---- phase 2: bulk read, still fully self-validating ----
        u32x4 q[16];
        {
            const char* bp = rowb + ug * 16;
            int rebulk = 0;
            for (;;) {
                BULK16(q, bp);
                u32 bad = 0;
#pragma unroll
                for (int i = 0; i < 16; i++)
                    bad |= (q[i][0] ^ tp) | (q[i][1] ^ tp)
                         | (q[i][2] ^ tp) | (q[i][3] ^ tp);
                if (!__any((int)((bad & 0xFFFF0000u) != 0))) break;
                if (++rebulk > MAXBULK) break;       // fail-safe, never hang
            }
        }

        // ---- strip tags -> A_lds ----
        {
            f16* dst = A_lds + sm * AP;
#pragma unroll
            for (int i = 0; i < 16; i++) {
                u32 p0 = (q[i][0] & 0xFFFFu) | (q[i][1] << 16);
                u32 p1 = (q[i][2] & 0xFFFFu) | (q[i][3] << 16);
                *(u64*)(dst + i * 16 + ug * 4) = (u64)p0 | ((u64)p1 << 32);
            }
        }
        __syncthreads();   // sync1: A_lds ready

        // ---- z = h @ Wrec (MFMA), wave tile 32m x 64n ----
        f32x4 acc[2][4];
#pragma unroll
        for (int mt = 0; mt < 2; mt++)
#pragma unroll
            for (int nt = 0; nt < 4; nt++) acc[mt][nt] = (f32x4)0.f;
#pragma unroll
        for (int ks = 0; ks < 8; ks++) {
            f16x8 Af[2];
#pragma unroll
            for (int mt = 0; mt < 2; mt++)
                Af[mt] = *(const f16x8*)(A_lds + (r * 32 + mt * 16 + mi) * AP
                                               + ks * 32 + kq * 8);
#pragma unroll
            for (int mt = 0; mt < 2; mt++)
#pragma unroll
                for (int nt = 0; nt < 4; nt++)
                    acc[mt][nt] = __builtin_amdgcn_mfma_f32_16x16x32_f16(
                        Af[mt], Bf[nt][ks], acc[mt][nt], 0, 0, 0);
        }
#pragma unroll
        for (int mt = 0; mt < 2; mt++)
#pragma unroll
            for (int nt = 0; nt < 4; nt++) {
                const int col = c * 64 + nt * 16 + mi;
                float* zp = z_lds + col * ZP + r * 32 + mt * 16 + kq * 4;
#pragma unroll
                for (int ri = 0; ri < 4; ri++) zp[ri] = acc[mt][nt][ri];
            }
        __syncthreads();   // sync2: z ready

        // ---- activations: 8 cells per thread ----
        float hv[8];
#pragma unroll
        for (int j = 0; j < 8; j++) {
            const int uu = ug * 8 + j;
            const float zi = z_lds[(0 * 32 + uu) * ZP + b_act] + (float)xzv[0][j];
            const float zj = z_lds[(1 * 32 + uu) * ZP + b_act] + (float)xzv[1][j];
            const float zf = z_lds[(2 * 32 + uu) * ZP + b_act] + (float)xzv[2][j] + 1.0f;
            const float zo = z_lds[(3 * 32 + uu) * ZP + b_act] + (float)xzv[3][j];
            const float si = 1.f / (1.f + __expf(-zi));
            const float sf = 1.f / (1.f + __expf(-zf));
            const float so = 1.f / (1.f + __expf(-zo));
            const float tj = 1.f - 2.f / (1.f + __expf(2.f * zj));
            cell[j] = sf * cell[j] + si * tj;
            hv[j] = so * (1.f - 2.f / (1.f + __expf(2.f * cell[j])));
        }

        // ---- publish tagged h (sc0, fire-and-forget) ----
        {
            const u32 tg = ((u32)(s + 1)) << 16;
            union { f16 h; unsigned short us; } cv;
            u32x4 st0, st1;
#pragma unroll
            for (int j = 0; j < 4; j++) { cv.h = (f16)hv[j];     st0[j] = (u32)cv.us | tg; }
#pragma unroll
            for (int j = 0; j < 4; j++) { cv.h = (f16)hv[4 + j]; st1[j] = (u32)cv.us | tg; }
            u32* hwp = hbd + ((s + 1) & 1) * (64 * 256) + b_act * 256 + sl * 32 + ug * 8;
            asm volatile(
                "global_store_dwordx4 %0, %1, off sc0\n\t"
                "global_store_dwordx4 %0, %2, off offset:16 sc0"
                :: "v"(hwp), "v"(st0), "v"(st1)
                : "memory");
        }
#pragma unroll
        for (int j = 0; j < 8; j++) pv[j] = hv[j];
        pt = t;
        // next step's sentinel vmcnt(0) overlaps these store acks with its
        // own load RT (max, not sum).
    }
    // final deferred out store
    {
        float* op = outb + (size_t)pt * 512;
        f32x4 o0 = {pv[0], pv[1], pv[2], pv[3]};
        f32x4 o1 = {pv[4], pv[5], pv[6], pv[7]};
        *(f32x4*)op = o0;
        *(f32x4*)(op + 4) = o1;
    }
}

// ---------------------------------------------------------------- launcher
extern "C" void kernel_launch(void* const* d_in, const int* in_sizes, int n_in,
                              void* d_out, int out_size, void* d_ws, size_t ws_size,
                              hipStream_t stream) {
    const float* x   = (const float*)d_in[0];
    const float* Wfw = (const float*)d_in[1];
    const float* bfw = (const float*)d_in[2];
    const float* Wbw = (const float*)d_in[3];
    const float* bbw = (const float*)d_in[4];
    float* out = (float*)d_out;

    f16* xzf   = (f16*)d_ws;                          // [64*512*1024]
    f16* xzb   = xzf + (size_t)64 * 512 * 1024;       // [64*512*1024]
    f16* wrec2 = xzb + (size_t)64 * 512 * 1024;       // [2*1024*256]
    u32* hbuf  = (u32*)(wrec2 + (size_t)2 * 1024 * 256);  // [2*2*64*256] tagged h
    u32* claim = hbuf + (size_t)2 * 2 * 64 * 256;         // [8] claim counters

    init_all<<<dim3(2048), 256, 0, stream>>>(Wfw, Wbw, wrec2, hbuf);
    gemm_xz<<<dim3(256, 8, 2), 256, 0, stream>>>(x, Wfw, Wbw, bfw, bbw, xzf, xzb);
    rec_persist<<<dim3(256), 256, 0, stream>>>(xzf, wrec2, hbuf, claim, out);

    (void)in_sizes; (void)n_in; (void)out_size; (void)ws_size;
}

// Round 9
// 2659.886 us; speedup vs baseline: 1.0782x; 1.0782x over previous
//
#include <hip/hip_runtime.h>

// Bidirectional LSTM: B=64, T=512, D=512 (feats k=h*64+c), U=256.
// W: [768,1024] fp32, gate order (i,j,f,o), forget bias 1.0.
// out [64,512,512] fp32 (fw units 0..255, bw 256..511), bw aligned to t.
//
// Structure = round-3 kernel (PASSED, rec_persist 2397us; R8 sentinel was
// a regression and is reverted), minimally edited:
//  - CU-UNIQUE claim: HW_ID bits[15:8] (SE/SH/CU) + atomicExch guard ensure
//    the 8 wgs/dir sit on 8 DISTINCT CUs (2 wgs/CU fit at 68KB LDS; a
//    CU-mate serializes compute and steals issue slots from MFMA).
//  - BATCHED out-stores: pv[8][8] in registers, flushed every 8 steps
//    (8x unrolled step loop -> static indexing, no scratch). Only 1 poll
//    in 8 pays the HBM write-ack drain in its vmcnt(0).
//  - bulk poll asm has EARLY-CLOBBER outputs (R4 lesson).
// Protocol unchanged: self-validating tagged words (tag<<16)|f16 through
// the XCD-local L2 (sc0), XCC_ID claim, bounded spins (never hangs).

typedef float f32x4 __attribute__((ext_vector_type(4)));
typedef _Float16 f16;
typedef _Float16 f16x4 __attribute__((ext_vector_type(4)));
typedef _Float16 f16x8 __attribute__((ext_vector_type(8)));
typedef unsigned int u32;
typedef unsigned int u32x4 __attribute__((ext_vector_type(4)));
typedef unsigned long long u64;

// ---------------------------------------------------------------- init
__global__ void init_all(const float* __restrict__ Wfw, const float* __restrict__ Wbw,
                         f16* __restrict__ wrec2, u32* __restrict__ hbuf) {
    const int i = blockIdx.x * blockDim.x + threadIdx.x;   // 0..524287
    const int dir = i >> 18;
    const int rem = i & 0x3FFFF;
    const int col = rem >> 8;        // 0..1023 : sl*128 + gg*32 + uu
    const int k   = rem & 255;
    const int sl  = col >> 7;
    const int gg  = (col & 127) >> 5;
    const int uu  = col & 31;
    const float* W = dir ? Wbw : Wfw;
    wrec2[i] = (f16)W[(size_t)(512 + k) * 1024 + gg * 256 + sl * 32 + uu];
    // tagged-h double buffer (65536 u32) + 8 claim counters + 512 CU cells.
    // zero = {tag 0, h 0.0f16} = valid initial state for step 0.
    if (i < 66056) hbuf[i] = 0u;
}

// ---------------------------------------------------------------- xz GEMM
#define BM 128
#define BN 128
#define BK 32
#define ASTR 40   // f16 per LDS row (32 + 8 pad)

__global__ __launch_bounds__(256)
void gemm_xz(const float* __restrict__ x,
             const float* __restrict__ Wfw, const float* __restrict__ Wbw,
             const float* __restrict__ bfw, const float* __restrict__ bbw,
             f16* __restrict__ xz_fw, f16* __restrict__ xz_bw) {
    const int dir = blockIdx.z;
    const float* __restrict__ W    = dir ? Wbw : Wfw;
    const float* __restrict__ bias = dir ? bbw : bfw;
    f16* __restrict__ xz = dir ? xz_bw : xz_fw;

    __shared__ __align__(16) f16 As[BM * ASTR];
    __shared__ __align__(16) f16 Bs[BN * ASTR];

    const int tid = threadIdx.x;
    const int m0 = blockIdx.x * BM;
    const int n0 = blockIdx.y * BN;

    const int lane = tid & 63;
    const int wave = tid >> 6;
    const int wm = (wave & 1) * 64;
    const int wn = (wave >> 1) * 64;
    const int mi = lane & 15;
    const int kq = lane >> 4;

    const int arow = tid >> 1;
    const int ahalf = (tid & 1) * 16;
    const int am = m0 + arow;
    const int bb = am >> 9;            // batch (T=512)
    const int t  = am & 511;
    const int kk = tid >> 3;
    const int nc = (tid & 7) * 16;

    f32x4 acc[4][4];
#pragma unroll
    for (int i = 0; i < 4; i++)
#pragma unroll
        for (int j = 0; j < 4; j++) acc[i][j] = (f32x4)0.f;

    for (int kt = 0; kt < 512; kt += BK) {
        float va[16], vb[16];
        {
            const int kbase = kt + ahalf;
            const int hh = kbase >> 6;
            const float* px = x + (((size_t)bb * 8 + hh) * 512 + t) * 64 + (kbase & 63);
#pragma unroll
            for (int i = 0; i < 4; i++) {
                f32x4 v = *(const f32x4*)(px + i * 4);
                va[i*4+0] = v[0]; va[i*4+1] = v[1]; va[i*4+2] = v[2]; va[i*4+3] = v[3];
            }
            const float* pw = W + (size_t)(kt + kk) * 1024 + n0 + nc;
#pragma unroll
            for (int i = 0; i < 4; i++) {
                f32x4 v = *(const f32x4*)(pw + i * 4);
                vb[i*4+0] = v[0]; vb[i*4+1] = v[1]; vb[i*4+2] = v[2]; vb[i*4+3] = v[3];
            }
        }
        __syncthreads();
        {
            f16* pa = &As[arow * ASTR + ahalf];
#pragma unroll
            for (int i = 0; i < 4; i++) {
                f16x4 s;
                s[0] = (f16)va[i*4+0]; s[1] = (f16)va[i*4+1];
                s[2] = (f16)va[i*4+2]; s[3] = (f16)va[i*4+3];
                *(f16x4*)(pa + i * 4) = s;
            }
#pragma unroll
            for (int i = 0; i < 16; i++)
                Bs[(nc + i) * ASTR + kk] = (f16)vb[i];
        }
        __syncthreads();
        f16x8 afr[4], bfr[4];
#pragma unroll
        for (int mt = 0; mt < 4; mt++)
            afr[mt] = *(const f16x8*)(&As[(wm + mt * 16 + mi) * ASTR + kq * 8]);
#pragma unroll
        for (int nt = 0; nt < 4; nt++)
            bfr[nt] = *(const f16x8*)(&Bs[(wn + nt * 16 + mi) * ASTR + kq * 8]);
#pragma unroll
        for (int mt = 0; mt < 4; mt++)
#pragma unroll
            for (int nt = 0; nt < 4; nt++)
                acc[mt][nt] = __builtin_amdgcn_mfma_f32_16x16x32_f16(
                    afr[mt], bfr[nt], acc[mt][nt], 0, 0, 0);
    }

    const int col = lane & 15;
    const int rbase = kq * 4;
#pragma unroll
    for (int mt = 0; mt < 4; mt++) {
#pragma unroll
        for (int nt = 0; nt < 4; nt++) {
            const int n = n0 + wn + nt * 16 + col;
            const float bv = bias[n];
#pragma unroll
            for (int r = 0; r < 4; r++) {
                const int mrow = m0 + wm + mt * 16 + rbase + r;
                xz[(size_t)mrow * 1024 + n] = (f16)(acc[mt][nt][r] + bv);
            }
        }
    }
}

// ---------------------------------------------------------------- recurrence
#define AP 264    // A_lds row stride (f16): 256 + 8 pad
#define ZP 67     // z_lds row stride (f32)
#define MAXSPIN 4000

// 16 x global_load_dwordx4 sc0 + vmcnt(0), one asm block, EARLY-CLOBBER.
#define BULK16(qv, ap)                                                        \
    asm volatile(                                                             \
        "global_load_dwordx4 %0, %16, off sc0\n\t"                            \
        "global_load_dwordx4 %1, %16, off offset:64 sc0\n\t"                  \
        "global_load_dwordx4 %2, %16, off offset:128 sc0\n\t"                 \
        "global_load_dwordx4 %3, %16, off offset:192 sc0\n\t"                 \
        "global_load_dwordx4 %4, %16, off offset:256 sc0\n\t"                 \
        "global_load_dwordx4 %5, %16, off offset:320 sc0\n\t"                 \
        "global_load_dwordx4 %6, %16, off offset:384 sc0\n\t"                 \
        "global_load_dwordx4 %7, %16, off offset:448 sc0\n\t"                 \
        "global_load_dwordx4 %8, %16, off offset:512 sc0\n\t"                 \
        "global_load_dwordx4 %9, %16, off offset:576 sc0\n\t"                 \
        "global_load_dwordx4 %10, %16, off offset:640 sc0\n\t"                \
        "global_load_dwordx4 %11, %16, off offset:704 sc0\n\t"                \
        "global_load_dwordx4 %12, %16, off offset:768 sc0\n\t"                \
        "global_load_dwordx4 %13, %16, off offset:832 sc0\n\t"                \
        "global_load_dwordx4 %14, %16, off offset:896 sc0\n\t"                \
        "global_load_dwordx4 %15, %16, off offset:960 sc0\n\t"                \
        "s_waitcnt vmcnt(0)"                                                  \
        : "=&v"(qv[0]), "=&v"(qv[1]), "=&v"(qv[2]), "=&v"(qv[3]),             \
          "=&v"(qv[4]), "=&v"(qv[5]), "=&v"(qv[6]), "=&v"(qv[7]),             \
          "=&v"(qv[8]), "=&v"(qv[9]), "=&v"(qv[10]), "=&v"(qv[11]),           \
          "=&v"(qv[12]), "=&v"(qv[13]), "=&v"(qv[14]), "=&v"(qv[15])          \
        : "v"(ap)                                                             \
        : "memory")

__global__ __launch_bounds__(256, 1)
void rec_persist(const f16* __restrict__ xz, const f16* __restrict__ wrec2,
                 u32* __restrict__ hbuf, u32* __restrict__ claimctr,
                 float* __restrict__ out) {
    // ---- CU-UNIQUE XCD-claim: one wg per physical CU; first 8 distinct-CU
    //      wgs on XCD0 -> dir0, on XCD1 -> dir1. (2 wgs/CU fit at this LDS;
    //      a CU-mate would serialize compute.) claimctr: [8] slot counters,
    //      then [2*256] CU-occupancy cells.
    __shared__ int cs[2];
    if (threadIdx.x == 0) {
        u32 xcd, hwid;
        asm("s_getreg_b32 %0, hwreg(HW_REG_XCC_ID, 0, 32)" : "=s"(xcd));
        asm("s_getreg_b32 %0, hwreg(HW_REG_HW_ID, 8, 8)" : "=s"(hwid)); // SE/SH/CU
        int d = -1, slv = 0;
        if (xcd < 2u) {
            u32 occ = atomicExch(&claimctr[8 + xcd * 256 + (hwid & 255u)], 1u);
            if (occ == 0u) {                       // first wg on this CU
                u32 slot = atomicAdd(&claimctr[xcd], 1u);
                if (slot < 8u) { d = (int)xcd; slv = (int)slot; }
            }
        }
        cs[0] = d; cs[1] = slv;
    }
    __syncthreads();
    const int dir = cs[0];
    const int sl  = cs[1];
    if (dir < 0) return;

    const f16* __restrict__ xzd = xz + (size_t)dir * 64 * 512 * 1024;
    const f16* __restrict__ wsl = wrec2 + ((size_t)dir * 1024 + sl * 128) * 256;
    u32* __restrict__ hbd = hbuf + (size_t)dir * 2 * 64 * 256;

    __shared__ __align__(16) f16  A_lds[64 * AP];
    __shared__ float z_lds[128 * ZP];

    const int tid = threadIdx.x;
    const int lane = tid & 63;
    const int w = tid >> 6;
    const int r = w >> 1, c = w & 1;   // 2x2 wave tiling
    const int mi = lane & 15, kq = lane >> 4;

    // recurrent weight slab resident in registers: 32 frags = 128 VGPRs
    f16x8 Bf[4][8];
#pragma unroll
    for (int nt = 0; nt < 4; nt++)
#pragma unroll
        for (int ks = 0; ks < 8; ks++)
            Bf[nt][ks] = *(const f16x8*)(wsl + (size_t)(c * 64 + nt * 16 + mi) * 256
                                             + ks * 32 + kq * 8);

    const int b_act = tid >> 2;        // batch row (0..63)
    const int ug = tid & 3;            // unit-octet within slice
    float cell[8];
#pragma unroll
    for (int j = 0; j < 8; j++) cell[j] = 0.f;

    const int sm = tid >> 2;           // staging: batch row (same as b_act)

    float pv[8][8];                    // 8 steps of deferred out values
    float* const outb = out + ((size_t)b_act * 512) * 512 + dir * 256 + sl * 32 + ug * 8;

    for (int s0 = 0; s0 < 512; s0 += 8) {
        // ---- flush previous 8-step block of out rows (fire-and-forget;
        //      only THIS block's first poll pays the HBM ack drain) ----
        if (s0) {
            const int sb = s0 - 8;
#pragma unroll
            for (int i = 0; i < 8; i++) {
                const int tf = dir ? (511 - (sb + i)) : (sb + i);
                float* op = outb + (size_t)tf * 512;
                f32x4 o0 = {pv[i][0], pv[i][1], pv[i][2], pv[i][3]};
                f32x4 o1 = {pv[i][4], pv[i][5], pv[i][6], pv[i][7]};
                *(f32x4*)op = o0;
                *(f32x4*)(op + 4) = o1;
            }
        }

#pragma unroll
        for (int ph = 0; ph < 8; ph++) {
            const int s = s0 + ph;
            const int t = dir ? (511 - s) : s;
            const u32 tp = (u32)s << 16;

            // ---- poll tagged h(s-1): full 64KB burst, self-validating ----
            const char* srcb = (const char*)(hbd + (ph & 1) * (64 * 256))
                             + (size_t)sm * 1024 + ug * 16;
            u32x4 q[16];
            BULK16(q, srcb);

            // ---- xz prefetch: overlaps the tag check + any retry ----
            f16x8 xzv[4];
            const f16* xp = xzd + ((size_t)b_act * 512 + t) * 1024 + sl * 32 + ug * 8;
#pragma unroll
            for (int g = 0; g < 4; g++) xzv[g] = *(const f16x8*)(xp + g * 256);

            int spins = 0;
            for (;;) {
                u32 bad = 0;
#pragma unroll
                for (int i = 0; i < 16; i++)
                    bad |= (q[i][0] ^ tp) | (q[i][1] ^ tp)
                         | (q[i][2] ^ tp) | (q[i][3] ^ tp);
                if (!__any((int)((bad & 0xFFFF0000u) != 0))) break;
                if (++spins > MAXSPIN) break;        // fail-safe, never hang
                BULK16(q, srcb);
            }

            // ---- strip tags -> A_lds ----
            {
                f16* dst = A_lds + sm * AP;
#pragma unroll
                for (int i = 0; i < 16; i++) {
                    u32 p0 = (q[i][0] & 0xFFFFu) | (q[i][1] << 16);
                    u32 p1 = (q[i][2] & 0xFFFFu) | (q[i][3] << 16);
                    *(u64*)(dst + i * 16 + ug * 4) = (u64)p0 | ((u64)p1 << 32);
                }
            }
            __syncthreads();   // sync1: A_lds ready

            // ---- z = h @ Wrec (MFMA), wave tile 32m x 64n ----
            f32x4 acc[2][4];
#pragma unroll
            for (int mt = 0; mt < 2; mt++)
#pragma unroll
                for (int nt = 0; nt < 4; nt++) acc[mt][nt] = (f32x4)0.f;
#pragma unroll
            for (int ks = 0; ks < 8; ks++) {
                f16x8 Af[2];
#pragma unroll
                for (int mt = 0; mt < 2; mt++)
                    Af[mt] = *(const f16x8*)(A_lds + (r * 32 + mt * 16 + mi) * AP
                                                   + ks * 32 + kq * 8);
#pragma unroll
                for (int mt = 0; mt < 2; mt++)
#pragma unroll
                    for (int nt = 0; nt < 4; nt++)
                        acc[mt][nt] = __builtin_amdgcn_mfma_f32_16x16x32_f16(
                            Af[mt], Bf[nt][ks], acc[mt][nt], 0, 0, 0);
            }
#pragma unroll
            for (int mt = 0; mt < 2; mt++)
#pragma unroll
                for (int nt = 0; nt < 4; nt++) {
                    const int col = c * 64 + nt * 16 + mi;
                    float* zp = z_lds + col * ZP + r * 32 + mt * 16 + kq * 4;
#pragma unroll
                    for (int ri = 0; ri < 4; ri++) zp[ri] = acc[mt][nt][ri];
                }
            __syncthreads();   // sync2: z ready

            // ---- activations: 8 cells per thread ----
            float hv[8];
#pragma unroll
            for (int j = 0; j < 8; j++) {
                const int uu = ug * 8 + j;
                const float zi = z_lds[(0 * 32 + uu) * ZP + b_act] + (float)xzv[0][j];
                const float zj = z_lds[(1 * 32 + uu) * ZP + b_act] + (float)xzv[1][j];
                const float zf = z_lds[(2 * 32 + uu) * ZP + b_act] + (float)xzv[2][j] + 1.0f;
                const float zo = z_lds[(3 * 32 + uu) * ZP + b_act] + (float)xzv[3][j];
                const float si = 1.f / (1.f + __expf(-zi));
                const float sf = 1.f / (1.f + __expf(-zf));
                const float so = 1.f / (1.f + __expf(-zo));
                const float tj = 1.f - 2.f / (1.f + __expf(2.f * zj));
                cell[j] = sf * cell[j] + si * tj;
                hv[j] = so * (1.f - 2.f / (1.f + __expf(2.f * cell[j])));
            }

            // ---- publish tagged h (sc0, fire-and-forget) ----
            {
                const u32 tg = ((u32)(s + 1)) << 16;
                union { f16 h; unsigned short us; } cv;
                u32x4 st0, st1;
#pragma unroll
                for (int j = 0; j < 4; j++) { cv.h = (f16)hv[j];     st0[j] = (u32)cv.us | tg; }
#pragma unroll
                for (int j = 0; j < 4; j++) { cv.h = (f16)hv[4 + j]; st1[j] = (u32)cv.us | tg; }
                u32* hwp = hbd + ((ph + 1) & 1) * (64 * 256) + b_act * 256 + sl * 32 + ug * 8;
                asm volatile(
                    "global_store_dwordx4 %0, %1, off sc0\n\t"
                    "global_store_dwordx4 %0, %2, off offset:16 sc0"
                    :: "v"(hwp), "v"(st0), "v"(st1)
                    : "memory");
            }
#pragma unroll
            for (int j = 0; j < 8; j++) pv[ph][j] = hv[j];
        }
    }
    // final block flush
    {
        const int sb = 504;
#pragma unroll
        for (int i = 0; i < 8; i++) {
            const int tf = dir ? (511 - (sb + i)) : (sb + i);
            float* op = outb + (size_t)tf * 512;
            f32x4 o0 = {pv[i][0], pv[i][1], pv[i][2], pv[i][3]};
            f32x4 o1 = {pv[i][4], pv[i][5], pv[i][6], pv[i][7]};
            *(f32x4*)op = o0;
            *(f32x4*)(op + 4) = o1;
        }
    }
}

// ---------------------------------------------------------------- launcher
extern "C" void kernel_launch(void* const* d_in, const int* in_sizes, int n_in,
                              void* d_out, int out_size, void* d_ws, size_t ws_size,
                              hipStream_t stream) {
    const float* x   = (const float*)d_in[0];
    const float* Wfw = (const float*)d_in[1];
    const float* bfw = (const float*)d_in[2];
    const float* Wbw = (const float*)d_in[3];
    const float* bbw = (const float*)d_in[4];
    float* out = (float*)d_out;

    f16* xzf   = (f16*)d_ws;                          // [64*512*1024]
    f16* xzb   = xzf + (size_t)64 * 512 * 1024;       // [64*512*1024]
    f16* wrec2 = xzb + (size_t)64 * 512 * 1024;       // [2*1024*256]
    u32* hbuf  = (u32*)(wrec2 + (size_t)2 * 1024 * 256);  // [2*2*64*256] tagged h
    u32* claim = hbuf + (size_t)2 * 2 * 64 * 256;     // [8] slots + [512] CU cells

    init_all<<<dim3(2048), 256, 0, stream>>>(Wfw, Wbw, wrec2, hbuf);
    gemm_xz<<<dim3(256, 8, 2), 256, 0, stream>>>(x, Wfw, Wbw, bfw, bbw, xzf, xzb);
    rec_persist<<<dim3(256), 256, 0, stream>>>(xzf, wrec2, hbuf, claim, out);

    (void)in_sizes; (void)n_in; (void)out_size; (void)ws_size;
}

// Round 11
// 2493.086 us; speedup vs baseline: 1.1504x; 1.0669x over previous
//
#include <hip/hip_runtime.h>

// Bidirectional LSTM: B=64, T=512, D=512 (feats k=h*64+c), U=256.
// W: [768,1024] fp32, gate order (i,j,f,o), forget bias 1.0.
// out [64,512,512] fp32 (fw units 0..255, bw 256..511), bw aligned to t.
//
// Structure = round-10 kernel (R3 protocol + batched out-store), with the
// MAXSPIN bailout hardened: 40000 spins (+s_sleep backoff after 64) so a
// rare scheduler hiccup during graph-replay/rocprof runs cannot trigger a
// silent stale-accept (R10's suspected one-replay flake). Fast path
// (0-2 poll rounds) unaffected.
//  - BATCHED out-stores: pv[8][8] in registers, flushed every 8 steps
//    (8x unrolled step loop -> static indexing). Only 1 poll in 8 pays the
//    HBM write-ack drain in its vmcnt(0). [A/B: R9 fast mode 2242 vs 2397]
//  - bulk poll asm has EARLY-CLOBBER outputs (R4 lesson).
// Protocol: self-validating tagged words (tag<<16)|f16 through the
// XCD-local L2 (sc0), first-8-arrival XCC_ID claim (unimodal; R9's
// CU-unique claim was bimodal and is NOT used), bounded spins.

typedef float f32x4 __attribute__((ext_vector_type(4)));
typedef _Float16 f16;
typedef _Float16 f16x4 __attribute__((ext_vector_type(4)));
typedef _Float16 f16x8 __attribute__((ext_vector_type(8)));
typedef unsigned int u32;
typedef unsigned int u32x4 __attribute__((ext_vector_type(4)));
typedef unsigned long long u64;

// ---------------------------------------------------------------- init
__global__ void init_all(const float* __restrict__ Wfw, const float* __restrict__ Wbw,
                         f16* __restrict__ wrec2, u32* __restrict__ hbuf) {
    const int i = blockIdx.x * blockDim.x + threadIdx.x;   // 0..524287
    const int dir = i >> 18;
    const int rem = i & 0x3FFFF;
    const int col = rem >> 8;        // 0..1023 : sl*128 + gg*32 + uu
    const int k   = rem & 255;
    const int sl  = col >> 7;
    const int gg  = (col & 127) >> 5;
    const int uu  = col & 31;
    const float* W = dir ? Wbw : Wfw;
    wrec2[i] = (f16)W[(size_t)(512 + k) * 1024 + gg * 256 + sl * 32 + uu];
    // tagged-h double buffer (65536 u32) + 8 claim counters.
    // zero = {tag 0, h 0.0f16} = valid initial state for step 0.
    if (i < 65544) hbuf[i] = 0u;
}

// ---------------------------------------------------------------- xz GEMM
#define BM 128
#define BN 128
#define BK 32
#define ASTR 40   // f16 per LDS row (32 + 8 pad)

__global__ __launch_bounds__(256)
void gemm_xz(const float* __restrict__ x,
             const float* __restrict__ Wfw, const float* __restrict__ Wbw,
             const float* __restrict__ bfw, const float* __restrict__ bbw,
             f16* __restrict__ xz_fw, f16* __restrict__ xz_bw) {
    const int dir = blockIdx.z;
    const float* __restrict__ W    = dir ? Wbw : Wfw;
    const float* __restrict__ bias = dir ? bbw : bfw;
    f16* __restrict__ xz = dir ? xz_bw : xz_fw;

    __shared__ __align__(16) f16 As[BM * ASTR];
    __shared__ __align__(16) f16 Bs[BN * ASTR];

    const int tid = threadIdx.x;
    const int m0 = blockIdx.x * BM;
    const int n0 = blockIdx.y * BN;

    const int lane = tid & 63;
    const int wave = tid >> 6;
    const int wm = (wave & 1) * 64;
    const int wn = (wave >> 1) * 64;
    const int mi = lane & 15;
    const int kq = lane >> 4;

    const int arow = tid >> 1;
    const int ahalf = (tid & 1) * 16;
    const int am = m0 + arow;
    const int bb = am >> 9;            // batch (T=512)
    const int t  = am & 511;
    const int kk = tid >> 3;
    const int nc = (tid & 7) * 16;

    f32x4 acc[4][4];
#pragma unroll
    for (int i = 0; i < 4; i++)
#pragma unroll
        for (int j = 0; j < 4; j++) acc[i][j] = (f32x4)0.f;

    for (int kt = 0; kt < 512; kt += BK) {
        float va[16], vb[16];
        {
            const int kbase = kt + ahalf;
            const int hh = kbase >> 6;
            const float* px = x + (((size_t)bb * 8 + hh) * 512 + t) * 64 + (kbase & 63);
#pragma unroll
            for (int i = 0; i < 4; i++) {
                f32x4 v = *(const f32x4*)(px + i * 4);
                va[i*4+0] = v[0]; va[i*4+1] = v[1]; va[i*4+2] = v[2]; va[i*4+3] = v[3];
            }
            const float* pw = W + (size_t)(kt + kk) * 1024 + n0 + nc;
#pragma unroll
            for (int i = 0; i < 4; i++) {
                f32x4 v = *(const f32x4*)(pw + i * 4);
                vb[i*4+0] = v[0]; vb[i*4+1] = v[1]; vb[i*4+2] = v[2]; vb[i*4+3] = v[3];
            }
        }
        __syncthreads();
        {
            f16* pa = &As[arow * ASTR + ahalf];
#pragma unroll
            for (int i = 0; i < 4; i++) {
                f16x4 s;
                s[0] = (f16)va[i*4+0]; s[1] = (f16)va[i*4+1];
                s[2] = (f16)va[i*4+2]; s[3] = (f16)va[i*4+3];
                *(f16x4*)(pa + i * 4) = s;
            }
#pragma unroll
            for (int i = 0; i < 16; i++)
                Bs[(nc + i) * ASTR + kk] = (f16)vb[i];
        }
        __syncthreads();
        f16x8 afr[4], bfr[4];
#pragma unroll
        for (int mt = 0; mt < 4; mt++)
            afr[mt] = *(const f16x8*)(&As[(wm + mt * 16 + mi) * ASTR + kq * 8]);
#pragma unroll
        for (int nt = 0; nt < 4; nt++)
            bfr[nt] = *(const f16x8*)(&Bs[(wn + nt * 16 + mi) * ASTR + kq * 8]);
#pragma unroll
        for (int mt = 0; mt < 4; mt++)
#pragma unroll
            for (int nt = 0; nt < 4; nt++)
                acc[mt][nt] = __builtin_amdgcn_mfma_f32_16x16x32_f16(
                    afr[mt], bfr[nt], acc[mt][nt], 0, 0, 0);
    }

    const int col = lane & 15;
    const int rbase = kq * 4;
#pragma unroll
    for (int mt = 0; mt < 4; mt++) {
#pragma unroll
        for (int nt = 0; nt < 4; nt++) {
            const int n = n0 + wn + nt * 16 + col;
            const float bv = bias[n];
#pragma unroll
            for (int r = 0; r < 4; r++) {
                const int mrow = m0 + wm + mt * 16 + rbase + r;
                xz[(size_t)mrow * 1024 + n] = (f16)(acc[mt][nt][r] + bv);
            }
        }
    }
}

// ---------------------------------------------------------------- recurrence
#define AP 264    // A_lds row stride (f16): 256 + 8 pad
#define ZP 67     // z_lds row stride (f32)
#define MAXSPIN 40000

// 16 x global_load_dwordx4 sc0 + vmcnt(0), one asm block, EARLY-CLOBBER.
#define BULK16(qv, ap)                                                        \
    asm volatile(                                                             \
        "global_load_dwordx4 %0, %16, off sc0\n\t"                            \
        "global_load_dwordx4 %1, %16, off offset:64 sc0\n\t"                  \
        "global_load_dwordx4 %2, %16, off offset:128 sc0\n\t"                 \
        "global_load_dwordx4 %3, %16, off offset:192 sc0\n\t"                 \
        "global_load_dwordx4 %4, %16, off offset:256 sc0\n\t"                 \
        "global_load_dwordx4 %5, %16, off offset:320 sc0\n\t"                 \
        "global_load_dwordx4 %6, %16, off offset:384 sc0\n\t"                 \
        "global_load_dwordx4 %7, %16, off offset:448 sc0\n\t"                 \
        "global_load_dwordx4 %8, %16, off offset:512 sc0\n\t"                 \
        "global_load_dwordx4 %9, %16, off offset:576 sc0\n\t"                 \
        "global_load_dwordx4 %10, %16, off offset:640 sc0\n\t"                \
        "global_load_dwordx4 %11, %16, off offset:704 sc0\n\t"                \
        "global_load_dwordx4 %12, %16, off offset:768 sc0\n\t"                \
        "global_load_dwordx4 %13, %16, off offset:832 sc0\n\t"                \
        "global_load_dwordx4 %14, %16, off offset:896 sc0\n\t"                \
        "global_load_dwordx4 %15, %16, off offset:960 sc0\n\t"                \
        "s_waitcnt vmcnt(0)"                                                  \
        : "=&v"(qv[0]), "=&v"(qv[1]), "=&v"(qv[2]), "=&v"(qv[3]),             \
          "=&v"(qv[4]), "=&v"(qv[5]), "=&v"(qv[6]), "=&v"(qv[7]),             \
          "=&v"(qv[8]), "=&v"(qv[9]), "=&v"(qv[10]), "=&v"(qv[11]),           \
          "=&v"(qv[12]), "=&v"(qv[13]), "=&v"(qv[14]), "=&v"(qv[15])          \
        : "v"(ap)                                                             \
        : "memory")

__global__ __launch_bounds__(256, 1)
void rec_persist(const f16* __restrict__ xz, const f16* __restrict__ wrec2,
                 u32* __restrict__ hbuf, u32* __restrict__ claimctr,
                 float* __restrict__ out) {
    // ---- XCD-claim (R3-style, unimodal): first 8 wgs on XCD0 -> dir0,
    //      first 8 on XCD1 -> dir1.
    __shared__ int cs[2];
    if (threadIdx.x == 0) {
        u32 xcd;
        asm("s_getreg_b32 %0, hwreg(HW_REG_XCC_ID, 0, 32)" : "=s"(xcd));
        int d = -1, slv = 0;
        if (xcd < 2u) {
            u32 slot = atomicAdd(&claimctr[xcd], 1u);
            if (slot < 8u) { d = (int)xcd; slv = (int)slot; }
        }
        cs[0] = d; cs[1] = slv;
    }
    __syncthreads();
    const int dir = cs[0];
    const int sl  = cs[1];
    if (dir < 0) return;

    const f16* __restrict__ xzd = xz + (size_t)dir * 64 * 512 * 1024;
    const f16* __restrict__ wsl = wrec2 + ((size_t)dir * 1024 + sl * 128) * 256;
    u32* __restrict__ hbd = hbuf + (size_t)dir * 2 * 64 * 256;

    __shared__ __align__(16) f16  A_lds[64 * AP];
    __shared__ float z_lds[128 * ZP];

    const int tid = threadIdx.x;
    const int lane = tid & 63;
    const int w = tid >> 6;
    const int r = w >> 1, c = w & 1;   // 2x2 wave tiling
    const int mi = lane & 15, kq = lane >> 4;

    // recurrent weight slab resident in registers: 32 frags = 128 VGPRs
    f16x8 Bf[4][8];
#pragma unroll
    for (int nt = 0; nt < 4; nt++)
#pragma unroll
        for (int ks = 0; ks < 8; ks++)
            Bf[nt][ks] = *(const f16x8*)(wsl + (size_t)(c * 64 + nt * 16 + mi) * 256
                                             + ks * 32 + kq * 8);

    const int b_act = tid >> 2;        // batch row (0..63)
    const int ug = tid & 3;            // unit-octet within slice
    float cell[8];
#pragma unroll
    for (int j = 0; j < 8; j++) cell[j] = 0.f;

    const int sm = tid >> 2;           // staging: batch row (same as b_act)

    float pv[8][8];                    // 8 steps of deferred out values
    float* const outb = out + ((size_t)b_act * 512) * 512 + dir * 256 + sl * 32 + ug * 8;

    for (int s0 = 0; s0 < 512; s0 += 8) {
        // ---- flush previous 8-step block of out rows (fire-and-forget;
        //      only THIS block's first poll pays the HBM ack drain) ----
        if (s0) {
            const int sb = s0 - 8;
#pragma unroll
            for (int i = 0; i < 8; i++) {
                const int tf = dir ? (511 - (sb + i)) : (sb + i);
                float* op = outb + (size_t)tf * 512;
                f32x4 o0 = {pv[i][0], pv[i][1], pv[i][2], pv[i][3]};
                f32x4 o1 = {pv[i][4], pv[i][5], pv[i][6], pv[i][7]};
                *(f32x4*)op = o0;
                *(f32x4*)(op + 4) = o1;
            }
        }

#pragma unroll
        for (int ph = 0; ph < 8; ph++) {
            const int s = s0 + ph;
            const int t = dir ? (511 - s) : s;
            const u32 tp = (u32)s << 16;

            // ---- poll tagged h(s-1): full 64KB burst, self-validating ----
            const char* srcb = (const char*)(hbd + (ph & 1) * (64 * 256))
                             + (size_t)sm * 1024 + ug * 16;
            u32x4 q[16];
            BULK16(q, srcb);

            // ---- xz prefetch: overlaps the tag check + any retry ----
            f16x8 xzv[4];
            const f16* xp = xzd + ((size_t)b_act * 512 + t) * 1024 + sl * 32 + ug * 8;
#pragma unroll
            for (int g = 0; g < 4; g++) xzv[g] = *(const f16x8*)(xp + g * 256);

            int spins = 0;
            for (;;) {
                u32 bad = 0;
#pragma unroll
                for (int i = 0; i < 16; i++)
                    bad |= (q[i][0] ^ tp) | (q[i][1] ^ tp)
                         | (q[i][2] ^ tp) | (q[i][3] ^ tp);
                if (!__any((int)((bad & 0xFFFF0000u) != 0))) break;
                if (++spins > MAXSPIN) break;        // fail-safe, never hang
                if (spins > 64) __builtin_amdgcn_s_sleep(1);  // backoff, rare
                BULK16(q, srcb);
            }

            // ---- strip tags -> A_lds ----
            {
                f16* dst = A_lds + sm * AP;
#pragma unroll
                for (int i = 0; i < 16; i++) {
                    u32 p0 = (q[i][0] & 0xFFFFu) | (q[i][1] << 16);
                    u32 p1 = (q[i][2] & 0xFFFFu) | (q[i][3] << 16);
                    *(u64*)(dst + i * 16 + ug * 4) = (u64)p0 | ((u64)p1 << 32);
                }
            }
            __syncthreads();   // sync1: A_lds ready

            // ---- z = h @ Wrec (MFMA), wave tile 32m x 64n ----
            f32x4 acc[2][4];
#pragma unroll
            for (int mt = 0; mt < 2; mt++)
#pragma unroll
                for (int nt = 0; nt < 4; nt++) acc[mt][nt] = (f32x4)0.f;
#pragma unroll
            for (int ks = 0; ks < 8; ks++) {
                f16x8 Af[2];
#pragma unroll
                for (int mt = 0; mt < 2; mt++)
                    Af[mt] = *(const f16x8*)(A_lds + (r * 32 + mt * 16 + mi) * AP
                                                   + ks * 32 + kq * 8);
#pragma unroll
                for (int mt = 0; mt < 2; mt++)
#pragma unroll
                    for (int nt = 0; nt < 4; nt++)
                        acc[mt][nt] = __builtin_amdgcn_mfma_f32_16x16x32_f16(
                            Af[mt], Bf[nt][ks], acc[mt][nt], 0, 0, 0);
            }
#pragma unroll
            for (int mt = 0; mt < 2; mt++)
#pragma unroll
                for (int nt = 0; nt < 4; nt++) {
                    const int col = c * 64 + nt * 16 + mi;
                    float* zp = z_lds + col * ZP + r * 32 + mt * 16 + kq * 4;
#pragma unroll
                    for (int ri = 0; ri < 4; ri++) zp[ri] = acc[mt][nt][ri];
                }
            __syncthreads();   // sync2: z ready

            // ---- activations: 8 cells per thread ----
            float hv[8];
#pragma unroll
            for (int j = 0; j < 8; j++) {
                const int uu = ug * 8 + j;
                const float zi = z_lds[(0 * 32 + uu) * ZP + b_act] + (float)xzv[0][j];
                const float zj = z_lds[(1 * 32 + uu) * ZP + b_act] + (float)xzv[1][j];
                const float zf = z_lds[(2 * 32 + uu) * ZP + b_act] + (float)xzv[2][j] + 1.0f;
                const float zo = z_lds[(3 * 32 + uu) * ZP + b_act] + (float)xzv[3][j];
                const float si = 1.f / (1.f + __expf(-zi));
                const float sf = 1.f / (1.f + __expf(-zf));
                const float so = 1.f / (1.f + __expf(-zo));
                const float tj = 1.f - 2.f / (1.f + __expf(2.f * zj));
                cell[j] = sf * cell[j] + si * tj;
                hv[j] = so * (1.f - 2.f / (1.f + __expf(2.f * cell[j])));
            }

            // ---- publish tagged h (sc0, fire-and-forget) ----
            {
                const u32 tg = ((u32)(s + 1)) << 16;
                union { f16 h; unsigned short us; } cv;
                u32x4 st0, st1;
#pragma unroll
                for (int j = 0; j < 4; j++) { cv.h = (f16)hv[j];     st0[j] = (u32)cv.us | tg; }
#pragma unroll
                for (int j = 0; j < 4; j++) { cv.h = (f16)hv[4 + j]; st1[j] = (u32)cv.us | tg; }
                u32* hwp = hbd + ((ph + 1) & 1) * (64 * 256) + b_act * 256 + sl * 32 + ug * 8;
                asm volatile(
                    "global_store_dwordx4 %0, %1, off sc0\n\t"
                    "global_store_dwordx4 %0, %2, off offset:16 sc0"
                    :: "v"(hwp), "v"(st0), "v"(st1)
                    : "memory");
            }
#pragma unroll
            for (int j = 0; j < 8; j++) pv[ph][j] = hv[j];
        }
    }
    // final block flush
    {
        const int sb = 504;
#pragma unroll
        for (int i = 0; i < 8; i++) {
            const int tf = dir ? (511 - (sb + i)) : (sb + i);
            float* op = outb + (size_t)tf * 512;
            f32x4 o0 = {pv[i][0], pv[i][1], pv[i][2], pv[i][3]};
            f32x4 o1 = {pv[i][4], pv[i][5], pv[i][6], pv[i][7]};
            *(f32x4*)op = o0;
            *(f32x4*)(op + 4) = o1;
        }
    }
}

// ---------------------------------------------------------------- launcher
extern "C" void kernel_launch(void* const* d_in, const int* in_sizes, int n_in,
                              void* d_out, int out_size, void* d_ws, size_t ws_size,
                              hipStream_t stream) {
    const float* x   = (const float*)d_in[0];
    const float* Wfw = (const float*)d_in[1];
    const float* bfw = (const float*)d_in[2];
    const float* Wbw = (const float*)d_in[3];
    const float* bbw = (const float*)d_in[4];
    float* out = (float*)d_out;

    f16* xzf   = (f16*)d_ws;                          // [64*512*1024]
    f16* xzb   = xzf + (size_t)64 * 512 * 1024;       // [64*512*1024]
    f16* wrec2 = xzb + (size_t)64 * 512 * 1024;       // [2*1024*256]
    u32* hbuf  = (u32*)(wrec2 + (size_t)2 * 1024 * 256);  // [2*2*64*256] tagged h
    u32* claim = hbuf + (size_t)2 * 2 * 64 * 256;         // [8] claim counters

    init_all<<<dim3(2048), 256, 0, stream>>>(Wfw, Wbw, wrec2, hbuf);
    gemm_xz<<<dim3(256, 8, 2), 256, 0, stream>>>(x, Wfw, Wbw, bfw, bbw, xzf, xzb);
    rec_persist<<<dim3(256), 256, 0, stream>>>(xzf, wrec2, hbuf, claim, out);

    (void)in_sizes; (void)n_in; (void)out_size; (void)ws_size;
}